// Round 17
// baseline (105.704 us; speedup 1.0000x reference)
//
#include <hip/hip_runtime.h>
#include <hip/hip_bf16.h>
#include <math.h>

#define NPTS 8192
#define KNN  20
#define NBLK (NPTS / 64)           // 128 sorted 64-blocks
#define NCELL 4096                 // 16^3 Morton cells
#define GLO  (-4.0f)
#define GINV (2.0f)

typedef __attribute__((ext_vector_type(8))) short short8v;
typedef __attribute__((ext_vector_type(4))) float f32x4v;

__device__ __forceinline__ int cellof(float v) {
    int c = (int)floorf((v - GLO) * GINV);
    return min(max(c, 0), 15);
}
__device__ __forceinline__ int spread4(int b) {
    return (b & 1) | ((b & 2) << 2) | ((b & 4) << 4) | ((b & 8) << 6);
}
// orderable encoding: unsigned compare == float compare
__device__ __forceinline__ unsigned fenc(float f) {
    unsigned u = __float_as_uint(f);
    return (u & 0x80000000u) ? ~u : (u | 0x80000000u);
}
__device__ __forceinline__ float fdec(unsigned k) {
    unsigned u = (k & 0x80000000u) ? (k & 0x7fffffffu) : ~k;
    return __uint_as_float(u);
}

// 64-lane bitonic sort, ascending by lane. Keys d, payload ji.
__device__ __forceinline__ void bitonic64(float& d, int& ji, int lane) {
#pragma unroll
    for (int k = 2; k <= 64; k <<= 1) {
#pragma unroll
        for (int j = k >> 1; j > 0; j >>= 1) {
            const float od = __shfl_xor(d, j);
            const int   oi = __shfl_xor(ji, j);
            const bool up      = ((lane & k) == 0);
            const bool lower   = ((lane & j) == 0);
            const bool takeMin = (up == lower);
            const bool sw = takeMin ? (od < d) : (od > d);
            d  = sw ? od : d;
            ji = sw ? oi : ji;
        }
    }
}

__device__ __forceinline__ void bitonic_clean64(float& d, int& ji, int lane) {
#pragma unroll
    for (int j = 32; j > 0; j >>= 1) {
        const float od = __shfl_xor(d, j);
        const int   oi = __shfl_xor(ji, j);
        const bool lower = ((lane & j) == 0);
        const bool sw = lower ? (od < d) : (od > d);
        d  = sw ? od : d;
        ji = sw ? oi : ji;
    }
}

// merge LDS hit-pool (cnt entries) into the resident sorted-64 list (ld,lj)
__device__ __forceinline__ void compact(float& ld, int& lj,
                                        const float* __restrict__ sd,
                                        const int* __restrict__ sj,
                                        int cnt, int lane) {
    __builtin_amdgcn_wave_barrier();          // order pool ds_writes before reads
    float bd = (lane < cnt) ? sd[lane] : INFINITY;
    int   bj = (lane < cnt) ? sj[lane] : -1;
    bitonic64(bd, bj, lane);
    const float rd = __shfl(bd, 63 - lane);
    const int   rj = __shfl(bj, 63 - lane);
    const bool sw = rd < ld;
    float md = sw ? rd : ld;
    int   mj = sw ? rj : lj;
    bitonic_clean64(md, mj, lane);
    ld = md; lj = mj;
}

// ---------------- weight restructure helpers ----------------
__device__ __forceinline__ void prep_w_elem(const float* __restrict__ W,
                                            float* __restrict__ Wc,
                                            int tid, int O, int C) {
    const int o = tid / C, k = tid % C;
    const float wa = W[o*2*C + k];
    const float wb = W[o*2*C + C + k];
    Wc[o*C + k]       = wa - wb;
    Wc[(O + o)*C + k] = wb;
}

__device__ __forceinline__ void prep_w_elem_b(const float* __restrict__ W,
                                              __hip_bfloat16* __restrict__ Wc,
                                              int tid, int O, int C) {
    const int o = tid / C, k = tid % C;
    const float wa = W[o*2*C + k];
    const float wb = W[o*2*C + C + k];
    Wc[o*C + k]       = __float2bfloat16(wa - wb);
    Wc[(O + o)*C + k] = __float2bfloat16(wb);
}

// ---------------- sortall: whole pre-knn chain in ONE kernel ----------------
__global__ __launch_bounds__(1024) void sortall(const float* __restrict__ x,
                                                const float* __restrict__ W0,
                                                const float* __restrict__ W1,
                                                const float* __restrict__ W2,
                                                float4* __restrict__ srt,
                                                float4* __restrict__ bming,
                                                float4* __restrict__ bmaxg,
                                                float* __restrict__ Wc0,
                                                __hip_bfloat16* __restrict__ Wc1,
                                                __hip_bfloat16* __restrict__ Wc2) {
    const int t = threadIdx.x;
    if (blockIdx.x != 0) {
        for (int g = (blockIdx.x - 1) * 1024 + t; g < 192 + 8192 + 32768; g += 8 * 1024) {
            if (g < 192)             prep_w_elem(W0, Wc0, g, 64, 3);
            else if (g < 192 + 8192) prep_w_elem_b(W1, Wc1, g - 192, 128, 64);
            else                     prep_w_elem_b(W2, Wc2, g - 8384, 256, 128);
        }
        return;
    }
    __shared__ int lh[NCELL];
    __shared__ int lw[NCELL];
    __shared__ int ls[1024];
    __shared__ unsigned abn[NBLK * 3], abx[NBLK * 3];

    float px[8], py[8], pz[8];
    int   pc[8];
    for (int u = t; u < NCELL; u += 1024) { lh[u] = 0; }
    for (int u = t; u < NBLK * 3; u += 1024) { abn[u] = 0xFFFFFFFFu; abx[u] = 0u; }
    __syncthreads();
#pragma unroll
    for (int u = 0; u < 8; ++u) {
        const int i = u * 1024 + t;
        const float a = x[3*i+0], b = x[3*i+1], c = x[3*i+2];
        px[u] = a; py[u] = b; pz[u] = c;
        pc[u] = spread4(cellof(a)) | (spread4(cellof(b)) << 1) | (spread4(cellof(c)) << 2);
        atomicAdd(&lh[pc[u]], 1);
    }
    __syncthreads();
    const int h0 = lh[4*t+0], h1 = lh[4*t+1], h2 = lh[4*t+2], h3 = lh[4*t+3];
    const int s0 = h0, s1 = s0 + h1, s2 = s1 + h2, s3 = s2 + h3;
    ls[t] = s3;
    __syncthreads();
    for (int off = 1; off < 1024; off <<= 1) {
        const int uu = (t >= off) ? ls[t - off] : 0;
        __syncthreads();
        ls[t] += uu;
        __syncthreads();
    }
    const int excl = ls[t] - s3;
    lw[4*t+0] = excl;      lw[4*t+1] = excl + s0;
    lw[4*t+2] = excl + s1; lw[4*t+3] = excl + s2;
    __syncthreads();
#pragma unroll
    for (int u = 0; u < 8; ++u) {
        const int i = u * 1024 + t;
        const int pos = atomicAdd(&lw[pc[u]], 1);
        srt[pos] = make_float4(px[u], py[u], pz[u], __int_as_float(i));
        const int blk = pos >> 6;
        atomicMin(&abn[blk*3+0], fenc(px[u])); atomicMax(&abx[blk*3+0], fenc(px[u]));
        atomicMin(&abn[blk*3+1], fenc(py[u])); atomicMax(&abx[blk*3+1], fenc(py[u]));
        atomicMin(&abn[blk*3+2], fenc(pz[u])); atomicMax(&abx[blk*3+2], fenc(pz[u]));
    }
    __syncthreads();
    if (t < NBLK) {
        bming[t] = make_float4(fdec(abn[3*t+0]), fdec(abn[3*t+1]), fdec(abn[3*t+2]), 0.0f);
        bmaxg[t] = make_float4(fdec(abx[3*t+0]), fdec(abx[3*t+1]), fdec(abx[3*t+2]), 0.0f);
    }
}

// ---------------- KNN + fused layer-0 ----------------
__global__ __launch_bounds__(256) void knn_kernel(const float4* __restrict__ srt,
                                                  const float4* __restrict__ bmin,
                                                  const float4* __restrict__ bmax,
                                                  const float* __restrict__ x,
                                                  const float* __restrict__ Wc0,
                                                  const float* __restrict__ b0,
                                                  int* __restrict__ idx_out,
                                                  ushort* __restrict__ h0out) {
    __shared__ float sdp[4][64];
    __shared__ int   sjp[4][64];
    const int lane = threadIdx.x & 63;
    const int wv   = threadIdx.x >> 6;
    const int s    = blockIdx.x * 4 + wv;
    float* sd = sdp[wv];
    int*   sj = sjp[wv];

    const float4 p = srt[s];
    const int qorig = __float_as_int(p.w);
    const int bq = s >> 6;
    const int wlo = max(bq - 3, 0);
    const int whi = min(bq + 3, NBLK - 1);

    const float4 own = srt[(bq << 6) + lane];
    float4 wb[6];
    bool   wvalid[6];
    const int woff[6] = {1, -1, 2, -2, 3, -3};
#pragma unroll
    for (int j = 0; j < 6; ++j) {
        const int bb = bq + woff[j];
        wvalid[j] = (bb >= 0) && (bb < NBLK);
        const int bc = min(max(bb, 0), NBLK - 1);
        wb[j] = srt[(bc << 6) + lane];
    }

    float ld, cm;
    int lj;
    {
        const float dx = p.x - own.x, dy = p.y - own.y, dz = p.z - own.z;
        ld = dx*dx + dy*dy + dz*dz;
        lj = __float_as_int(own.w);
        bitonic64(ld, lj, lane);
        cm = __shfl(ld, KNN);
    }
    int cnt = 0;

#define APPEND(M, D, C4)                                                      \
    if (M) {                                                                  \
        const int tot = __popcll(M);                                          \
        if (cnt + tot > 64) {                                                 \
            compact(ld, lj, sd, sj, cnt, lane);                               \
            cm = __shfl(ld, KNN);                                             \
            cnt = 0;                                                          \
        }                                                                     \
        const int below = __builtin_amdgcn_mbcnt_hi(                          \
            (unsigned)((M) >> 32),                                            \
            __builtin_amdgcn_mbcnt_lo((unsigned)(M), 0));                     \
        const bool h = ((M) >> lane) & 1ull;                                  \
        if (h) { sd[cnt + below] = D; sj[cnt + below] = __float_as_int(C4.w); } \
        cnt += tot;                                                           \
    }

#pragma unroll
    for (int j = 0; j < 6; ++j) {
        const float dx = p.x - wb[j].x, dy = p.y - wb[j].y, dz = p.z - wb[j].z;
        const float d = dx*dx + dy*dy + dz*dz;
        const unsigned long long m = __ballot(wvalid[j] && (d < cm));
        APPEND(m, d, wb[j])
    }
    if (cnt > 0) { compact(ld, lj, sd, sj, cnt, lane); cm = __shfl(ld, KNN); cnt = 0; }

    unsigned long long mlo, mhi;
    {
        const float4 n0 = bmin[lane],      x0 = bmax[lane];
        const float4 n1 = bmin[lane + 64], x1 = bmax[lane + 64];
        float ax = fmaxf(fmaxf(n0.x - p.x, p.x - x0.x), 0.0f);
        float ay = fmaxf(fmaxf(n0.y - p.y, p.y - x0.y), 0.0f);
        float az = fmaxf(fmaxf(n0.z - p.z, p.z - x0.z), 0.0f);
        const float lb0 = ax*ax + ay*ay + az*az;
        ax = fmaxf(fmaxf(n1.x - p.x, p.x - x1.x), 0.0f);
        ay = fmaxf(fmaxf(n1.y - p.y, p.y - x1.y), 0.0f);
        az = fmaxf(fmaxf(n1.z - p.z, p.z - x1.z), 0.0f);
        const float lb1 = ax*ax + ay*ay + az*az;
        const bool h0 = (lb0 < cm) && (lane < wlo || lane > whi);
        const bool h1 = (lb1 < cm) && (lane + 64 < wlo || lane + 64 > whi);
        mlo = __ballot(h0);
        mhi = __ballot(h1);
    }

    while (mlo | mhi) {
        int bb0;
        if (mlo) { bb0 = __ffsll(mlo) - 1;      mlo &= (mlo - 1); }
        else     { bb0 = 64 + __ffsll(mhi) - 1; mhi &= (mhi - 1); }
        const bool has1 = (mlo | mhi) != 0;
        int bb1 = bb0;
        if (has1) {
            if (mlo) { bb1 = __ffsll(mlo) - 1;      mlo &= (mlo - 1); }
            else     { bb1 = 64 + __ffsll(mhi) - 1; mhi &= (mhi - 1); }
        }
        const float4 c0 = srt[(bb0 << 6) + lane];
        const float4 c1 = srt[(bb1 << 6) + lane];
        const float dx0 = p.x - c0.x, dy0 = p.y - c0.y, dz0 = p.z - c0.z;
        const float d0 = dx0*dx0 + dy0*dy0 + dz0*dz0;
        const float dx1 = p.x - c1.x, dy1 = p.y - c1.y, dz1 = p.z - c1.z;
        const float d1 = dx1*dx1 + dy1*dy1 + dz1*dz1;
        const unsigned long long m0 = __ballot(d0 < cm);
        APPEND(m0, d0, c0)
        const unsigned long long m1 = __ballot(has1 && (d1 < cm));
        APPEND(m1, d1, c1)
    }
    if (cnt > 0) compact(ld, lj, sd, sj, cnt, lane);
#undef APPEND

    if (lane >= 1 && lane <= KNN) idx_out[qorig * KNN + lane - 1] = lj;

    // ---- fused layer 0 ----
    {
        const int nk = lane / 3;
        const int c  = lane % 3;
        const int nj = __shfl(lj, 1 + nk);
        float v = 0.0f;
        if (lane < 60) v = x[3 * nj + c];
        __builtin_amdgcn_wave_barrier();
        sd[lane] = v;
        __builtin_amdgcn_wave_barrier();
        const float w0 = Wc0[3 * lane + 0];
        const float w1 = Wc0[3 * lane + 1];
        const float w2 = Wc0[3 * lane + 2];
        const float u0 = Wc0[3 * (64 + lane) + 0];
        const float u1 = Wc0[3 * (64 + lane) + 1];
        const float u2 = Wc0[3 * (64 + lane) + 2];
        const float base = p.x * w0 + p.y * w1 + p.z * w2 + b0[lane];
        float m = -INFINITY;
#pragma unroll
        for (int k = 0; k < KNN; ++k) {
            const float xj0 = sd[3*k+0], xj1 = sd[3*k+1], xj2 = sd[3*k+2];
            m = fmaxf(m, xj0*u0 + xj1*u1 + xj2*u2);
        }
        const float o = fmaxf(base + m, 0.0f);
        const __hip_bfloat16 hb = __float2bfloat16(o);
        h0out[qorig * 64 + lane] = *reinterpret_cast<const ushort*>(&hb);
    }
}

// ---------------- bf16 MFMA GEMM (layer 1): T(f32) = H(bf16) * Wc^T(bf16) ----------------
__global__ __launch_bounds__(256) void gemm_bf16(const ushort* __restrict__ H,
                                                 const ushort* __restrict__ Wc,
                                                 float* __restrict__ T,
                                                 int Kk, int Mm) {
    const int l  = threadIdx.x & 63;
    const int w  = threadIdx.x >> 6;
    const int m  = l & 15;
    const int kg = l >> 4;
    const int row_t = blockIdx.x * 64 + w * 16;
    const int col0  = blockIdx.y * 64;

    f32x4v acc0 = {0.f, 0.f, 0.f, 0.f};
    f32x4v acc1 = acc0, acc2 = acc0, acc3 = acc0;

    const ushort* hp = H  + (row_t + m) * Kk + kg * 8;
    const ushort* wp = Wc + (col0 + m) * Kk + kg * 8;
    const int wstep = 16 * Kk;

    for (int k0 = 0; k0 < Kk; k0 += 32) {
        const short8v a  = *reinterpret_cast<const short8v*>(hp + k0);
        const short8v b0 = *reinterpret_cast<const short8v*>(wp + k0);
        const short8v b1 = *reinterpret_cast<const short8v*>(wp + wstep + k0);
        const short8v b2 = *reinterpret_cast<const short8v*>(wp + 2 * wstep + k0);
        const short8v b3 = *reinterpret_cast<const short8v*>(wp + 3 * wstep + k0);
        acc0 = __builtin_amdgcn_mfma_f32_16x16x32_bf16(a, b0, acc0, 0, 0, 0);
        acc1 = __builtin_amdgcn_mfma_f32_16x16x32_bf16(a, b1, acc1, 0, 0, 0);
        acc2 = __builtin_amdgcn_mfma_f32_16x16x32_bf16(a, b2, acc2, 0, 0, 0);
        acc3 = __builtin_amdgcn_mfma_f32_16x16x32_bf16(a, b3, acc3, 0, 0, 0);
    }

    const int orow = row_t + kg * 4;
#pragma unroll
    for (int r = 0; r < 4; ++r) {
        float* trow = &T[(orow + r) * Mm + col0 + m];
        trow[0]  = acc0[r];
        trow[16] = acc1[r];
        trow[32] = acc2[r];
        trow[48] = acc3[r];
    }
}

// ---------------- fused layer-2: maxrelu(T1)->h1(LDS) then h1 x Wc2 -> T2 ----------------
// grid (128, 2): block = 64 rows x 256 cols. Phase 1 computes the 64-row h1
// tile in LDS (bf16, padded stride 136 -> 2-way-bank A reads). Phase 2 MFMAs
// LDS-h1 against Wc2. by=0 cols 0..255 (base) -> d_out; by=1 cols 256..511
// (u part) -> T2u.  T1 is read-only here (T2 lives elsewhere) -> no race.
__global__ __launch_bounds__(256) void gemm2_fused(const float* __restrict__ T1,
                                                   const int* __restrict__ idx,
                                                   const float* __restrict__ b1,
                                                   const ushort* __restrict__ Wc2,
                                                   float* __restrict__ outb,
                                                   float* __restrict__ T2u) {
    __shared__ ushort lh1[64 * 136];
    __shared__ int sidx[64 * KNN];
    const int t = threadIdx.x;
    const int r0 = blockIdx.x * 64;
    const int by = blockIdx.y;

    for (int u = t; u < 64 * KNN; u += 256) sidx[u] = idx[r0 * KNN + u];
    __syncthreads();

    // phase 1: h1 tile (identical math to old maxrelu<128>)
    {
        const int oq = t & 31;            // channel quad 0..31 (ch = oq*4)
        const int p0 = t >> 5;            // 0..7
#pragma unroll
        for (int mm = 0; mm < 8; ++mm) {
            const int pl = p0 + mm * 8;   // local point 0..63
            const int gi = r0 + pl;
            float4 mx = make_float4(-INFINITY, -INFINITY, -INFINITY, -INFINITY);
            const int sb = pl * KNN;
#pragma unroll
            for (int k = 0; k < KNN; ++k) {
                const float4 v = *reinterpret_cast<const float4*>(
                    &T1[sidx[sb + k] * 256 + 128 + oq * 4]);
                mx.x = fmaxf(mx.x, v.x); mx.y = fmaxf(mx.y, v.y);
                mx.z = fmaxf(mx.z, v.z); mx.w = fmaxf(mx.w, v.w);
            }
            const float4 b = *reinterpret_cast<const float4*>(&T1[gi * 256 + oq * 4]);
            const float4 bv = *reinterpret_cast<const float4*>(&b1[oq * 4]);
            const float o0 = fmaxf(b.x + bv.x + mx.x, 0.0f);
            const float o1 = fmaxf(b.y + bv.y + mx.y, 0.0f);
            const float o2 = fmaxf(b.z + bv.z + mx.z, 0.0f);
            const float o3 = fmaxf(b.w + bv.w + mx.w, 0.0f);
            const __hip_bfloat16 h0 = __float2bfloat16(o0);
            const __hip_bfloat16 h1 = __float2bfloat16(o1);
            const __hip_bfloat16 h2 = __float2bfloat16(o2);
            const __hip_bfloat16 h3 = __float2bfloat16(o3);
            ushort4 u;
            u.x = *reinterpret_cast<const ushort*>(&h0);
            u.y = *reinterpret_cast<const ushort*>(&h1);
            u.z = *reinterpret_cast<const ushort*>(&h2);
            u.w = *reinterpret_cast<const ushort*>(&h3);
            *reinterpret_cast<ushort4*>(&lh1[pl * 136 + oq * 4]) = u;
        }
    }
    __syncthreads();

    // phase 2: MFMA LDS-h1 (64x128) x Wc2 cols [by*256, +256)
    {
        const int l  = t & 63;
        const int w  = t >> 6;
        const int m  = l & 15;
        const int kg = l >> 4;
        const int row_l = w * 16 + m;

        f32x4v acc[16];
#pragma unroll
        for (int ct = 0; ct < 16; ++ct) acc[ct] = (f32x4v){0.f, 0.f, 0.f, 0.f};

        const ushort* wbase = Wc2 + (by * 256 + m) * 128 + kg * 8;
#pragma unroll
        for (int kc = 0; kc < 4; ++kc) {
            const short8v a = *reinterpret_cast<const short8v*>(
                &lh1[row_l * 136 + kc * 32 + kg * 8]);
#pragma unroll
            for (int ct = 0; ct < 16; ++ct) {
                const short8v b = *reinterpret_cast<const short8v*>(
                    wbase + ct * 16 * 128 + kc * 32);
                acc[ct] = __builtin_amdgcn_mfma_f32_16x16x32_bf16(a, b, acc[ct], 0, 0, 0);
            }
        }

        float* dst = (by == 0) ? outb : T2u;
        const int orow0 = r0 + w * 16 + kg * 4;
#pragma unroll
        for (int ct = 0; ct < 16; ++ct) {
#pragma unroll
            for (int r = 0; r < 4; ++r) {
                dst[(orow0 + r) * 256 + ct * 16 + m] = acc[ct][r];
            }
        }
    }
}

// ---------------- final: out[i] = relu(base(d_out,own) + b2 + max_k T2u[nj]) ----------------
// In-place on d_out: each element read only by its own writer thread.
__global__ __launch_bounds__(256) void maxrelu_final(const float* __restrict__ T2u,
                                                     const int* __restrict__ idx,
                                                     const float* __restrict__ bias,
                                                     float* __restrict__ outb) {
    const int pi = threadIdx.x >> 6;       // 4 points/block
    const int oq = threadIdx.x & 63;       // channel quad (ch = oq*4, 256 ch)
    const int i  = blockIdx.x * 4 + pi;
    __shared__ int sidx[4 * KNN];
    if (threadIdx.x < 4 * KNN)
        sidx[threadIdx.x] = idx[blockIdx.x * 4 * KNN + threadIdx.x];
    __syncthreads();
    const int sb = pi * KNN;
    float4 m = make_float4(-INFINITY, -INFINITY, -INFINITY, -INFINITY);
#pragma unroll
    for (int k = 0; k < KNN; ++k) {
        const float4 v = *reinterpret_cast<const float4*>(&T2u[sidx[sb + k] * 256 + oq * 4]);
        m.x = fmaxf(m.x, v.x); m.y = fmaxf(m.y, v.y);
        m.z = fmaxf(m.z, v.z); m.w = fmaxf(m.w, v.w);
    }
    const float4 b = *reinterpret_cast<const float4*>(&outb[i * 256 + oq * 4]);
    const float4 bv = *reinterpret_cast<const float4*>(&bias[oq * 4]);
    float4 o;
    o.x = fmaxf(b.x + bv.x + m.x, 0.0f);
    o.y = fmaxf(b.y + bv.y + m.y, 0.0f);
    o.z = fmaxf(b.z + bv.z + m.z, 0.0f);
    o.w = fmaxf(b.w + bv.w + m.w, 0.0f);
    *reinterpret_cast<float4*>(&outb[i * 256 + oq * 4]) = o;
}

extern "C" void kernel_launch(void* const* d_in, const int* in_sizes, int n_in,
                              void* d_out, int out_size, void* d_ws, size_t ws_size,
                              hipStream_t stream) {
    const float* x  = (const float*)d_in[0];
    const float* W0 = (const float*)d_in[1];
    const float* b0 = (const float*)d_in[2];
    const float* W1 = (const float*)d_in[3];
    const float* b1 = (const float*)d_in[4];
    const float* W2 = (const float*)d_in[5];
    const float* b2 = (const float*)d_in[6];
    float* out = (float*)d_out;
    char*  ws  = (char*)d_ws;

    int*            idx  = (int*)(ws + 0);                   // 655360
    float*          Wc0  = (float*)(ws + 655360);            // 1536
    __hip_bfloat16* Wc1  = (__hip_bfloat16*)(ws + 656896);   // 32 KB
    __hip_bfloat16* Wc2  = (__hip_bfloat16*)(ws + 722432);   // 128 KB
    float*          bufA = (float*)(ws + 984576);            // 16 MB: T1 (8MB) + T2u (8MB)
    void*           bufB = (void*)(ws + 17761792);           // 4 MB (h0: bf16)

    float* T1  = bufA;                                       // 8192 x 256 f32
    float* T2u = (float*)((char*)bufA + 8388608);            // 8192 x 256 f32

    // knn-phase scratch aliases bufA (dead before gemm_bf16 writes T1)
    float4* srt  = (float4*)((char*)bufA + 131072);          // 128 KB
    float4* bmin = (float4*)((char*)bufA + 442368);          // 2 KB
    float4* bmax = (float4*)((char*)bufA + 444416);          // 2 KB

    // whole pre-knn chain (sort + AABB + weight restructure) in one kernel
    sortall<<<9, 1024, 0, stream>>>(x, W0, W1, W2, srt, bmin, bmax, Wc0, Wc1, Wc2);

    // knn + fused layer 0: idx + h0(8192x64 bf16) in one kernel
    knn_kernel<<<NPTS / 4, 256, 0, stream>>>(srt, bmin, bmax, x, Wc0, b0,
                                             idx, (ushort*)bufB);

    // layer 1: h0 -> T1(8192x256 f32)
    gemm_bf16<<<dim3(128, 4), 256, 0, stream>>>((const ushort*)bufB, (const ushort*)Wc1,
                                                T1, 64, 256);

    // layer 2 fused: maxrelu(T1)->h1(LDS) x Wc2 -> base to d_out, u to T2u
    gemm2_fused<<<dim3(128, 2), 256, 0, stream>>>(T1, idx, b1, (const ushort*)Wc2,
                                                  out, T2u);

    // final: out = relu(base + b2 + gathered max of T2u)   (in-place on d_out)
    maxrelu_final<<<NPTS / 4, 256, 0, stream>>>(T2u, idx, b2, out);
}

// Round 18
// 89.396 us; speedup vs baseline: 1.1824x; 1.1824x over previous
//
#include <hip/hip_runtime.h>
#include <hip/hip_bf16.h>
#include <math.h>

#define NPTS 8192
#define KNN  20
#define NBLK (NPTS / 64)           // 128 sorted 64-blocks
#define NCELL 4096                 // 16^3 Morton cells
#define GLO  (-4.0f)
#define GINV (2.0f)

typedef __attribute__((ext_vector_type(8))) short short8v;
typedef __attribute__((ext_vector_type(4))) float f32x4v;

__device__ __forceinline__ int cellof(float v) {
    int c = (int)floorf((v - GLO) * GINV);
    return min(max(c, 0), 15);
}
__device__ __forceinline__ int spread4(int b) {
    return (b & 1) | ((b & 2) << 2) | ((b & 4) << 4) | ((b & 8) << 6);
}
// orderable encoding: unsigned compare == float compare
__device__ __forceinline__ unsigned fenc(float f) {
    unsigned u = __float_as_uint(f);
    return (u & 0x80000000u) ? ~u : (u | 0x80000000u);
}
__device__ __forceinline__ float fdec(unsigned k) {
    unsigned u = (k & 0x80000000u) ? (k & 0x7fffffffu) : ~k;
    return __uint_as_float(u);
}

// 64-lane bitonic sort, ascending by lane. Keys d, payload ji.
__device__ __forceinline__ void bitonic64(float& d, int& ji, int lane) {
#pragma unroll
    for (int k = 2; k <= 64; k <<= 1) {
#pragma unroll
        for (int j = k >> 1; j > 0; j >>= 1) {
            const float od = __shfl_xor(d, j);
            const int   oi = __shfl_xor(ji, j);
            const bool up      = ((lane & k) == 0);
            const bool lower   = ((lane & j) == 0);
            const bool takeMin = (up == lower);
            const bool sw = takeMin ? (od < d) : (od > d);
            d  = sw ? od : d;
            ji = sw ? oi : ji;
        }
    }
}

__device__ __forceinline__ void bitonic_clean64(float& d, int& ji, int lane) {
#pragma unroll
    for (int j = 32; j > 0; j >>= 1) {
        const float od = __shfl_xor(d, j);
        const int   oi = __shfl_xor(ji, j);
        const bool lower = ((lane & j) == 0);
        const bool sw = lower ? (od < d) : (od > d);
        d  = sw ? od : d;
        ji = sw ? oi : ji;
    }
}

// merge LDS hit-pool (cnt entries) into the resident sorted-64 list (ld,lj)
__device__ __forceinline__ void compact(float& ld, int& lj,
                                        const float* __restrict__ sd,
                                        const int* __restrict__ sj,
                                        int cnt, int lane) {
    __builtin_amdgcn_wave_barrier();          // order pool ds_writes before reads
    float bd = (lane < cnt) ? sd[lane] : INFINITY;
    int   bj = (lane < cnt) ? sj[lane] : -1;
    bitonic64(bd, bj, lane);
    const float rd = __shfl(bd, 63 - lane);
    const int   rj = __shfl(bj, 63 - lane);
    const bool sw = rd < ld;
    float md = sw ? rd : ld;
    int   mj = sw ? rj : lj;
    bitonic_clean64(md, mj, lane);
    ld = md; lj = mj;
}

// ---------------- weight restructure helpers ----------------
__device__ __forceinline__ void prep_w_elem(const float* __restrict__ W,
                                            float* __restrict__ Wc,
                                            int tid, int O, int C) {
    const int o = tid / C, k = tid % C;
    const float wa = W[o*2*C + k];
    const float wb = W[o*2*C + C + k];
    Wc[o*C + k]       = wa - wb;
    Wc[(O + o)*C + k] = wb;
}

__device__ __forceinline__ void prep_w_elem_b(const float* __restrict__ W,
                                              __hip_bfloat16* __restrict__ Wc,
                                              int tid, int O, int C) {
    const int o = tid / C, k = tid % C;
    const float wa = W[o*2*C + k];
    const float wb = W[o*2*C + C + k];
    Wc[o*C + k]       = __float2bfloat16(wa - wb);
    Wc[(O + o)*C + k] = __float2bfloat16(wb);
}

// ---------------- sortall: whole pre-knn chain in ONE kernel ----------------
__global__ __launch_bounds__(1024) void sortall(const float* __restrict__ x,
                                                const float* __restrict__ W0,
                                                const float* __restrict__ W1,
                                                const float* __restrict__ W2,
                                                float4* __restrict__ srt,
                                                float4* __restrict__ bming,
                                                float4* __restrict__ bmaxg,
                                                float* __restrict__ Wc0,
                                                __hip_bfloat16* __restrict__ Wc1,
                                                __hip_bfloat16* __restrict__ Wc2) {
    const int t = threadIdx.x;
    if (blockIdx.x != 0) {
        for (int g = (blockIdx.x - 1) * 1024 + t; g < 192 + 8192 + 32768; g += 8 * 1024) {
            if (g < 192)             prep_w_elem(W0, Wc0, g, 64, 3);
            else if (g < 192 + 8192) prep_w_elem_b(W1, Wc1, g - 192, 128, 64);
            else                     prep_w_elem_b(W2, Wc2, g - 8384, 256, 128);
        }
        return;
    }
    __shared__ int lh[NCELL];
    __shared__ int lw[NCELL];
    __shared__ int ls[1024];
    __shared__ unsigned abn[NBLK * 3], abx[NBLK * 3];

    float px[8], py[8], pz[8];
    int   pc[8];
    for (int u = t; u < NCELL; u += 1024) { lh[u] = 0; }
    for (int u = t; u < NBLK * 3; u += 1024) { abn[u] = 0xFFFFFFFFu; abx[u] = 0u; }
    __syncthreads();
#pragma unroll
    for (int u = 0; u < 8; ++u) {
        const int i = u * 1024 + t;
        const float a = x[3*i+0], b = x[3*i+1], c = x[3*i+2];
        px[u] = a; py[u] = b; pz[u] = c;
        pc[u] = spread4(cellof(a)) | (spread4(cellof(b)) << 1) | (spread4(cellof(c)) << 2);
        atomicAdd(&lh[pc[u]], 1);
    }
    __syncthreads();
    const int h0 = lh[4*t+0], h1 = lh[4*t+1], h2 = lh[4*t+2], h3 = lh[4*t+3];
    const int s0 = h0, s1 = s0 + h1, s2 = s1 + h2, s3 = s2 + h3;
    ls[t] = s3;
    __syncthreads();
    for (int off = 1; off < 1024; off <<= 1) {
        const int uu = (t >= off) ? ls[t - off] : 0;
        __syncthreads();
        ls[t] += uu;
        __syncthreads();
    }
    const int excl = ls[t] - s3;
    lw[4*t+0] = excl;      lw[4*t+1] = excl + s0;
    lw[4*t+2] = excl + s1; lw[4*t+3] = excl + s2;
    __syncthreads();
#pragma unroll
    for (int u = 0; u < 8; ++u) {
        const int i = u * 1024 + t;
        const int pos = atomicAdd(&lw[pc[u]], 1);
        srt[pos] = make_float4(px[u], py[u], pz[u], __int_as_float(i));
        const int blk = pos >> 6;
        atomicMin(&abn[blk*3+0], fenc(px[u])); atomicMax(&abx[blk*3+0], fenc(px[u]));
        atomicMin(&abn[blk*3+1], fenc(py[u])); atomicMax(&abx[blk*3+1], fenc(py[u]));
        atomicMin(&abn[blk*3+2], fenc(pz[u])); atomicMax(&abx[blk*3+2], fenc(pz[u]));
    }
    __syncthreads();
    if (t < NBLK) {
        bming[t] = make_float4(fdec(abn[3*t+0]), fdec(abn[3*t+1]), fdec(abn[3*t+2]), 0.0f);
        bmaxg[t] = make_float4(fdec(abx[3*t+0]), fdec(abx[3*t+1]), fdec(abx[3*t+2]), 0.0f);
    }
}

// ---------------- KNN + fused layer-0 ----------------
__global__ __launch_bounds__(256) void knn_kernel(const float4* __restrict__ srt,
                                                  const float4* __restrict__ bmin,
                                                  const float4* __restrict__ bmax,
                                                  const float* __restrict__ x,
                                                  const float* __restrict__ Wc0,
                                                  const float* __restrict__ b0,
                                                  int* __restrict__ idx_out,
                                                  ushort* __restrict__ h0out) {
    __shared__ float sdp[4][64];
    __shared__ int   sjp[4][64];
    const int lane = threadIdx.x & 63;
    const int wv   = threadIdx.x >> 6;
    const int s    = blockIdx.x * 4 + wv;
    float* sd = sdp[wv];
    int*   sj = sjp[wv];

    const float4 p = srt[s];
    const int qorig = __float_as_int(p.w);
    const int bq = s >> 6;
    const int wlo = max(bq - 3, 0);
    const int whi = min(bq + 3, NBLK - 1);

    const float4 own = srt[(bq << 6) + lane];
    float4 wb[6];
    bool   wvalid[6];
    const int woff[6] = {1, -1, 2, -2, 3, -3};
#pragma unroll
    for (int j = 0; j < 6; ++j) {
        const int bb = bq + woff[j];
        wvalid[j] = (bb >= 0) && (bb < NBLK);
        const int bc = min(max(bb, 0), NBLK - 1);
        wb[j] = srt[(bc << 6) + lane];
    }

    float ld, cm;
    int lj;
    {
        const float dx = p.x - own.x, dy = p.y - own.y, dz = p.z - own.z;
        ld = dx*dx + dy*dy + dz*dz;
        lj = __float_as_int(own.w);
        bitonic64(ld, lj, lane);
        cm = __shfl(ld, KNN);
    }
    int cnt = 0;

#define APPEND(M, D, C4)                                                      \
    if (M) {                                                                  \
        const int tot = __popcll(M);                                          \
        if (cnt + tot > 64) {                                                 \
            compact(ld, lj, sd, sj, cnt, lane);                               \
            cm = __shfl(ld, KNN);                                             \
            cnt = 0;                                                          \
        }                                                                     \
        const int below = __builtin_amdgcn_mbcnt_hi(                          \
            (unsigned)((M) >> 32),                                            \
            __builtin_amdgcn_mbcnt_lo((unsigned)(M), 0));                     \
        const bool h = ((M) >> lane) & 1ull;                                  \
        if (h) { sd[cnt + below] = D; sj[cnt + below] = __float_as_int(C4.w); } \
        cnt += tot;                                                           \
    }

#pragma unroll
    for (int j = 0; j < 6; ++j) {
        const float dx = p.x - wb[j].x, dy = p.y - wb[j].y, dz = p.z - wb[j].z;
        const float d = dx*dx + dy*dy + dz*dz;
        const unsigned long long m = __ballot(wvalid[j] && (d < cm));
        APPEND(m, d, wb[j])
    }
    if (cnt > 0) { compact(ld, lj, sd, sj, cnt, lane); cm = __shfl(ld, KNN); cnt = 0; }

    unsigned long long mlo, mhi;
    {
        const float4 n0 = bmin[lane],      x0 = bmax[lane];
        const float4 n1 = bmin[lane + 64], x1 = bmax[lane + 64];
        float ax = fmaxf(fmaxf(n0.x - p.x, p.x - x0.x), 0.0f);
        float ay = fmaxf(fmaxf(n0.y - p.y, p.y - x0.y), 0.0f);
        float az = fmaxf(fmaxf(n0.z - p.z, p.z - x0.z), 0.0f);
        const float lb0 = ax*ax + ay*ay + az*az;
        ax = fmaxf(fmaxf(n1.x - p.x, p.x - x1.x), 0.0f);
        ay = fmaxf(fmaxf(n1.y - p.y, p.y - x1.y), 0.0f);
        az = fmaxf(fmaxf(n1.z - p.z, p.z - x1.z), 0.0f);
        const float lb1 = ax*ax + ay*ay + az*az;
        const bool h0 = (lb0 < cm) && (lane < wlo || lane > whi);
        const bool h1 = (lb1 < cm) && (lane + 64 < wlo || lane + 64 > whi);
        mlo = __ballot(h0);
        mhi = __ballot(h1);
    }

    while (mlo | mhi) {
        int bb0;
        if (mlo) { bb0 = __ffsll(mlo) - 1;      mlo &= (mlo - 1); }
        else     { bb0 = 64 + __ffsll(mhi) - 1; mhi &= (mhi - 1); }
        const bool has1 = (mlo | mhi) != 0;
        int bb1 = bb0;
        if (has1) {
            if (mlo) { bb1 = __ffsll(mlo) - 1;      mlo &= (mlo - 1); }
            else     { bb1 = 64 + __ffsll(mhi) - 1; mhi &= (mhi - 1); }
        }
        const float4 c0 = srt[(bb0 << 6) + lane];
        const float4 c1 = srt[(bb1 << 6) + lane];
        const float dx0 = p.x - c0.x, dy0 = p.y - c0.y, dz0 = p.z - c0.z;
        const float d0 = dx0*dx0 + dy0*dy0 + dz0*dz0;
        const float dx1 = p.x - c1.x, dy1 = p.y - c1.y, dz1 = p.z - c1.z;
        const float d1 = dx1*dx1 + dy1*dy1 + dz1*dz1;
        const unsigned long long m0 = __ballot(d0 < cm);
        APPEND(m0, d0, c0)
        const unsigned long long m1 = __ballot(has1 && (d1 < cm));
        APPEND(m1, d1, c1)
    }
    if (cnt > 0) compact(ld, lj, sd, sj, cnt, lane);
#undef APPEND

    if (lane >= 1 && lane <= KNN) idx_out[qorig * KNN + lane - 1] = lj;

    // ---- fused layer 0 ----
    {
        const int nk = lane / 3;
        const int c  = lane % 3;
        const int nj = __shfl(lj, 1 + nk);
        float v = 0.0f;
        if (lane < 60) v = x[3 * nj + c];
        __builtin_amdgcn_wave_barrier();
        sd[lane] = v;
        __builtin_amdgcn_wave_barrier();
        const float w0 = Wc0[3 * lane + 0];
        const float w1 = Wc0[3 * lane + 1];
        const float w2 = Wc0[3 * lane + 2];
        const float u0 = Wc0[3 * (64 + lane) + 0];
        const float u1 = Wc0[3 * (64 + lane) + 1];
        const float u2 = Wc0[3 * (64 + lane) + 2];
        const float base = p.x * w0 + p.y * w1 + p.z * w2 + b0[lane];
        float m = -INFINITY;
#pragma unroll
        for (int k = 0; k < KNN; ++k) {
            const float xj0 = sd[3*k+0], xj1 = sd[3*k+1], xj2 = sd[3*k+2];
            m = fmaxf(m, xj0*u0 + xj1*u1 + xj2*u2);
        }
        const float o = fmaxf(base + m, 0.0f);
        const __hip_bfloat16 hb = __float2bfloat16(o);
        h0out[qorig * 64 + lane] = *reinterpret_cast<const ushort*>(&hb);
    }
}

// ---------------- bf16 MFMA GEMM: T(f32) = H(bf16, NxK) * Wc^T(bf16, MxK) ----------------
__global__ __launch_bounds__(256) void gemm_bf16(const ushort* __restrict__ H,
                                                 const ushort* __restrict__ Wc,
                                                 float* __restrict__ T,
                                                 int Kk, int Mm) {
    const int l  = threadIdx.x & 63;
    const int w  = threadIdx.x >> 6;
    const int m  = l & 15;
    const int kg = l >> 4;
    const int row_t = blockIdx.x * 64 + w * 16;
    const int col0  = blockIdx.y * 64;

    f32x4v acc0 = {0.f, 0.f, 0.f, 0.f};
    f32x4v acc1 = acc0, acc2 = acc0, acc3 = acc0;

    const ushort* hp = H  + (row_t + m) * Kk + kg * 8;
    const ushort* wp = Wc + (col0 + m) * Kk + kg * 8;
    const int wstep = 16 * Kk;

    for (int k0 = 0; k0 < Kk; k0 += 32) {
        const short8v a  = *reinterpret_cast<const short8v*>(hp + k0);
        const short8v b0 = *reinterpret_cast<const short8v*>(wp + k0);
        const short8v b1 = *reinterpret_cast<const short8v*>(wp + wstep + k0);
        const short8v b2 = *reinterpret_cast<const short8v*>(wp + 2 * wstep + k0);
        const short8v b3 = *reinterpret_cast<const short8v*>(wp + 3 * wstep + k0);
        acc0 = __builtin_amdgcn_mfma_f32_16x16x32_bf16(a, b0, acc0, 0, 0, 0);
        acc1 = __builtin_amdgcn_mfma_f32_16x16x32_bf16(a, b1, acc1, 0, 0, 0);
        acc2 = __builtin_amdgcn_mfma_f32_16x16x32_bf16(a, b2, acc2, 0, 0, 0);
        acc3 = __builtin_amdgcn_mfma_f32_16x16x32_bf16(a, b3, acc3, 0, 0, 0);
    }

    const int orow = row_t + kg * 4;
#pragma unroll
    for (int r = 0; r < 4; ++r) {
        float* trow = &T[(orow + r) * Mm + col0 + m];
        trow[0]  = acc0[r];
        trow[16] = acc1[r];
        trow[32] = acc2[r];
        trow[48] = acc3[r];
    }
}

// ---------------- gather + max + bias + relu (float4/thread, optional bf16 out) ----------------
template<int O, int OUT_BF16>
__global__ __launch_bounds__(256) void maxrelu_kernel(const float* __restrict__ T,
                                                      const int* __restrict__ idx,
                                                      const float* __restrict__ bias,
                                                      void* __restrict__ outv) {
    constexpr int Q   = O / 4;
    constexpr int PPB = 256 / Q;
    constexpr int M2  = 2 * O;
    const int pi = threadIdx.x / Q;
    const int oq = threadIdx.x & (Q - 1);
    const int i  = blockIdx.x * PPB + pi;
    __shared__ int sidx[PPB * KNN];
    for (int t = threadIdx.x; t < PPB * KNN; t += 256)
        sidx[t] = idx[blockIdx.x * PPB * KNN + t];
    __syncthreads();
    const int sb = pi * KNN;
    float4 m = make_float4(-INFINITY, -INFINITY, -INFINITY, -INFINITY);
#pragma unroll
    for (int k = 0; k < KNN; ++k) {
        const float4 v = *reinterpret_cast<const float4*>(&T[sidx[sb + k] * M2 + O + oq * 4]);
        m.x = fmaxf(m.x, v.x); m.y = fmaxf(m.y, v.y);
        m.z = fmaxf(m.z, v.z); m.w = fmaxf(m.w, v.w);
    }
    const float4 b = *reinterpret_cast<const float4*>(&T[i * M2 + oq * 4]);
    const float4 bv = *reinterpret_cast<const float4*>(&bias[oq * 4]);
    float4 o;
    o.x = fmaxf(b.x + bv.x + m.x, 0.0f);
    o.y = fmaxf(b.y + bv.y + m.y, 0.0f);
    o.z = fmaxf(b.z + bv.z + m.z, 0.0f);
    o.w = fmaxf(b.w + bv.w + m.w, 0.0f);
    if (OUT_BF16) {
        const __hip_bfloat16 h0 = __float2bfloat16(o.x);
        const __hip_bfloat16 h1 = __float2bfloat16(o.y);
        const __hip_bfloat16 h2 = __float2bfloat16(o.z);
        const __hip_bfloat16 h3 = __float2bfloat16(o.w);
        ushort4 u;
        u.x = *reinterpret_cast<const ushort*>(&h0);
        u.y = *reinterpret_cast<const ushort*>(&h1);
        u.z = *reinterpret_cast<const ushort*>(&h2);
        u.w = *reinterpret_cast<const ushort*>(&h3);
        *reinterpret_cast<ushort4*>(reinterpret_cast<ushort*>(outv) + i * O + oq * 4) = u;
    } else {
        *reinterpret_cast<float4*>(reinterpret_cast<float*>(outv) + i * O + oq * 4) = o;
    }
}

extern "C" void kernel_launch(void* const* d_in, const int* in_sizes, int n_in,
                              void* d_out, int out_size, void* d_ws, size_t ws_size,
                              hipStream_t stream) {
    const float* x  = (const float*)d_in[0];
    const float* W0 = (const float*)d_in[1];
    const float* b0 = (const float*)d_in[2];
    const float* W1 = (const float*)d_in[3];
    const float* b1 = (const float*)d_in[4];
    const float* W2 = (const float*)d_in[5];
    const float* b2 = (const float*)d_in[6];
    float* out = (float*)d_out;
    char*  ws  = (char*)d_ws;

    int*            idx  = (int*)(ws + 0);                   // 655360
    float*          Wc0  = (float*)(ws + 655360);            // 1536
    __hip_bfloat16* Wc1  = (__hip_bfloat16*)(ws + 656896);   // 32 KB
    __hip_bfloat16* Wc2  = (__hip_bfloat16*)(ws + 722432);   // 128 KB
    float*          bufA = (float*)(ws + 984576);            // 16 MB (T: fp32)
    void*           bufB = (void*)(ws + 17761792);           // 4 MB (h: bf16)

    // knn-phase scratch aliases bufA (dead before gemm_bf16 writes bufA)
    float4* srt  = (float4*)((char*)bufA + 131072);          // 128 KB
    float4* bmin = (float4*)((char*)bufA + 442368);          // 2 KB
    float4* bmax = (float4*)((char*)bufA + 444416);          // 2 KB

    // whole pre-knn chain (sort + AABB + weight restructure) in one kernel
    sortall<<<9, 1024, 0, stream>>>(x, W0, W1, W2, srt, bmin, bmax, Wc0, Wc1, Wc2);

    // knn + fused layer 0: idx + h0(8192x64 bf16) in one kernel
    knn_kernel<<<NPTS / 4, 256, 0, stream>>>(srt, bmin, bmax, x, Wc0, b0,
                                             idx, (ushort*)bufB);

    // layer 1: h0 -> T1(8192x256 f32) -> h1(8192x128 bf16)
    gemm_bf16<<<dim3(128, 4), 256, 0, stream>>>((const ushort*)bufB, (const ushort*)Wc1,
                                                bufA, 64, 256);
    maxrelu_kernel<128, 1><<<NPTS / 8, 256, 0, stream>>>(bufA, idx, b1, bufB);

    // layer 2: h1 -> T2(8192x512 f32) -> out(8192x256 f32)
    gemm_bf16<<<dim3(128, 8), 256, 0, stream>>>((const ushort*)bufB, (const ushort*)Wc2,
                                                bufA, 128, 512);
    maxrelu_kernel<256, 0><<<NPTS / 4, 256, 0, stream>>>(bufA, idx, b2, out);
}